// Round 8
// baseline (129.798 us; speedup 1.0000x reference)
//
#include <hip/hip_runtime.h>

#define EPSF 1e-5f

typedef _Float16 half8 __attribute__((ext_vector_type(8)));
typedef _Float16 half4v __attribute__((ext_vector_type(4)));
typedef float f32x4 __attribute__((ext_vector_type(4)));

__device__ __forceinline__ float clamp01(float x){ return fminf(fmaxf(x, 0.f), 1.f); }

// ---------------- prep: weight repack->f16 + bn constant folding ----------------
// Column pairing: B-tile0 col n holds oc=2n, tile1 col n holds oc=2n+1.
// w1h[col32][k160]  k = dy*32 + dx*4 + ic (ic<3, dx<5 used; rest zero)
// w2h[tap][col32][ic32], w3h[tap][oc64][ic32] (natural), w4h[oc16][k1024]
// bnc: [0,32) s1scale(1/4 folded) [32,64) s1shift [64,96) s2scale [96,128) s2shift
//      [128,192) s3scale [192,256) s3shift [256,266) s4scale [266,276) s4shift
__global__ __launch_bounds__(256) void k_prep(
    const float* __restrict__ w1, const float* __restrict__ w2,
    const float* __restrict__ w3, const float* __restrict__ w4,
    const float* __restrict__ g1, const float* __restrict__ b1, const float* __restrict__ m1, const float* __restrict__ v1,
    const float* __restrict__ g2, const float* __restrict__ b2, const float* __restrict__ m2, const float* __restrict__ v2,
    const float* __restrict__ g3, const float* __restrict__ b3, const float* __restrict__ m3, const float* __restrict__ v3,
    const float* __restrict__ g4, const float* __restrict__ b4, const float* __restrict__ m4, const float* __restrict__ v4,
    _Float16* __restrict__ w1h, _Float16* __restrict__ w2h, _Float16* __restrict__ w3h,
    _Float16* __restrict__ w4h, float* __restrict__ bnc)
{
  const int t = blockIdx.x*256 + threadIdx.x;   // grid 128 -> 32768 threads
  if (t < 5120) {                               // w1h: 32 cols x 160 k
    int c = t / 160, k = t - c*160;
    int oc = (c < 16) ? 2*c : 2*(c-16)+1;
    int dy = k >> 5, rem = k & 31, dx = rem >> 2, ic = rem & 3;
    float val = (dx < 5 && ic < 3) ? w1[(oc*3+ic)*25 + dy*5 + dx] : 0.f;
    w1h[t] = (_Float16)val;
  }
  for (int i = t; i < 25600; i += 32768) {
    int tap = i >> 10, r = i & 1023, c = r >> 5, ic = r & 31;
    int oc = (c < 16) ? 2*c : 2*(c-16)+1;
    w2h[i] = (_Float16)w2[(oc*32+ic)*25 + tap];
  }
  for (int i = t; i < 51200; i += 32768) {
    int tap = i >> 11, r = i & 2047, oc = r >> 5, ic = r & 31;
    w3h[i] = (_Float16)w3[(oc*32+ic)*25 + tap];
  }
  for (int i = t; i < 16384; i += 32768) {
    int oc = i >> 10, k = i & 1023, pos = k >> 6, ic = k & 63;
    float val = (oc < 10) ? w4[(oc*64+ic)*16 + pos] : 0.f;
    w4h[i] = (_Float16)val;
  }
  if (t < 32) {
    float inv = g1[t] / sqrtf(v1[t] + EPSF);
    bnc[t] = 0.25f*inv; bnc[32+t] = b1[t] - m1[t]*inv;
    float i2 = g2[t] / sqrtf(v2[t] + EPSF);
    bnc[64+t] = 0.25f*i2; bnc[96+t] = b2[t] - m2[t]*i2;
  }
  if (t < 64) {
    float i3 = g3[t] / sqrtf(v3[t] + EPSF);
    bnc[128+t] = 0.25f*i3; bnc[192+t] = b3[t] - m3[t]*i3;
  }
  if (t < 10) {
    float i4 = g4[t] / sqrtf(v4[t] + EPSF);
    bnc[256+t] = i4; bnc[266+t] = b4[t] - m4[t]*i4;
  }
}

// ---------------- fused: all 4 stages, one image per block, 512 thr / 8 waves ------
// Wave->tile: s1: wave w = (M-tile w&3) x (N-tile w>>2); s2 same; s3: waves 0-3.
// LDS overlays (byte offsets, 32000 B):
//   ph0:   Bx1 f16[35][160] @0 (11200)   Img f32[3][32][32] @11264 (12288)
//   ph2-3: P2  f16[20][20][40] @0 (32000)
//   ph4-5: P3  f16[12][12][40] @0 (11520)   Ip3 f16[16][64] @11520 (2048)
//   ph6:   S4P f32[160] @13568 (640)
__global__ __launch_bounds__(512, 6) void k_fused(
    const float* __restrict__ x,
    const _Float16* __restrict__ w1h, const _Float16* __restrict__ w2h,
    const _Float16* __restrict__ w3h, const _Float16* __restrict__ w4h,
    const float* __restrict__ bnc, float* __restrict__ out)
{
  __shared__ __align__(16) char arena[32000];
  _Float16* Bx1 = (_Float16*)arena;            // [35][160]
  float*    Img = (float*)(arena + 11264);     // [3][32][32] f32
  _Float16* P2  = (_Float16*)arena;            // [20][20][40]
  _Float16* P3  = (_Float16*)arena;            // [12][12][40]
  _Float16* Ip3 = (_Float16*)(arena + 11520);  // [16][64]
  float*    S4P = (float*)(arena + 13568);     // [160]

  const int img = blockIdx.x;
  const int tid = threadIdx.x;
  const int w   = __builtin_amdgcn_readfirstlane(tid >> 6);  // wave 0..7 (SGPR)
  const int l   = tid & 63;
  const int row = l & 15;          // A-row / B-col / C-col lane index
  const int kg  = l >> 4;          // k-group (8 halfs each)
  const int mtb = w & 3;           // M-tile for s1/s2
  const int ntb = w >> 2;          // N-tile (0/1) for s1/s2

  // ---------- ph0a: coalesced image stage (fp32, 12KB) ----------
  {
    const float4* src = (const float4*)(x + img*3072);
    float4* dst = (float4*)Img;
    dst[tid] = src[tid];
    if (tid < 256) dst[tid + 512] = src[tid + 512];
  }
  __syncthreads();                               // b0: Img ready

  // ---------- ph0b: Bx1[y][x][ic] = 2x2 box of zero-padded input (from LDS) ----------
  for (int j = tid; j < 1400; j += 512) {        // y<35, x<40 (x>=34 all-zero taps)
    int y = j / 40, xx = j - y*40;
    float s0 = 0.f, s1 = 0.f, s2 = 0.f;
    #pragma unroll
    for (int r = 0; r < 2; ++r) {
      int iy = y - 2 + r;
      if ((unsigned)iy < 32u) {
        #pragma unroll
        for (int cc = 0; cc < 2; ++cc) {
          int ix = xx - 2 + cc;
          if ((unsigned)ix < 32u) {
            const float* ip = Img + iy*32 + ix;
            s0 += ip[0]; s1 += ip[1024]; s2 += ip[2048];
          }
        }
      }
    }
    half4v h; h[0] = (_Float16)s0; h[1] = (_Float16)s1; h[2] = (_Float16)s2; h[3] = (_Float16)0.f;
    *(half4v*)(Bx1 + y*160 + xx*4) = h;
  }
  __syncthreads();                               // b1: Bx1 ready

  // ---------- ph1: s1 MFMA  wave = (4 py-rows) x (16 oc-cols), K=160 ----------
  f32x4 acc1[4];
  {
    half8 B1[5];
    #pragma unroll
    for (int dy = 0; dy < 5; ++dy)
      B1[dy] = *(const half8*)(w1h + (ntb*16 + row)*160 + dy*32 + kg*8);
    #pragma unroll
    for (int mt = 0; mt < 4; ++mt) acc1[mt] = (f32x4){0,0,0,0};
    const int xoff = 8*(row + kg);               // halfs; 16B aligned
    #pragma unroll
    for (int mt = 0; mt < 4; ++mt) {
      const int py = mtb*4 + mt;
      #pragma unroll
      for (int dy = 0; dy < 5; ++dy) {
        half8 av = *(const half8*)(Bx1 + (2*py + dy)*160 + xoff);
        acc1[mt] = __builtin_amdgcn_mfma_f32_16x16x32_f16(av, B1[dy], acc1[mt], 0, 0, 0);
      }
    }
  }
  __syncthreads();                               // b2: all Bx1 reads done

  // ---------- ph2: zero P2 border + write s1 output (oc = 2*row + ntb) ----------
  for (int j = tid; j < 1600; j += 512) {        // 400 pos x 4 half8 (ic 0..31)
    int u = j & 3, pos = j >> 2;
    int a = pos/20, c = pos - a*20;
    bool interior = ((unsigned)(a-2) < 16u) & ((unsigned)(c-2) < 16u);
    if (!interior) *(half8*)(P2 + pos*40 + u*8) = (half8)(_Float16)0.f;
  }
  {
    const int oc = 2*row + ntb;
    const float sA = bnc[oc], hA = bnc[32 + oc];
    #pragma unroll
    for (int mt = 0; mt < 4; ++mt) {
      const int py = mtb*4 + mt;
      #pragma unroll
      for (int r = 0; r < 4; ++r) {
        int pcol = kg*4 + r;
        int idx = ((py+2)*20 + pcol+2)*40;
        P2[idx + oc] = (_Float16)clamp01(fmaf(acc1[mt][r], sA, hA));
      }
    }
  }
  __syncthreads();                               // b3: P2 complete

  // ---------- ph3: s2 MFMA, wave = (16 pixels) x (16 oc), rolling 2-row window ----
  f32x4 a2 = {0,0,0,0};
  {
    const int pixel = mtb*16 + row;
    const int py = pixel >> 3, px = pixel & 7;
    const _Float16* base = P2 + ((2*py)*20 + 2*px)*40 + kg*8;
    half8 RA[6], RB[6];
    #pragma unroll
    for (int c = 0; c < 6; ++c) RA[c] = *(const half8*)(base + c*40);
    #pragma unroll
    for (int c = 0; c < 6; ++c) RB[c] = *(const half8*)(base + 800 + c*40);
    const _Float16* wb = w2h + (ntb*16 + row)*32 + kg*8;
    half8 cw = *(const half8*)(wb);
    #pragma unroll
    for (int dy = 0; dy < 5; ++dy) {
      half8 cs[6];
      #pragma unroll
      for (int c = 0; c < 6; ++c) cs[c] = RA[c] + RB[c];
      if (dy < 4) {
        #pragma unroll
        for (int c = 0; c < 6; ++c) {
          half8 nv = *(const half8*)(base + (dy+2)*800 + c*40);
          if ((dy & 1) == 0) RA[c] = nv; else RB[c] = nv;
        }
      }
      #pragma unroll
      for (int dx = 0; dx < 5; ++dx) {
        const int tap = dy*5 + dx;
        const int tn = (tap < 24) ? tap + 1 : 24;
        half8 nw = *(const half8*)(wb + tn*1024);
        half8 av = cs[dx] + cs[dx+1];
        a2 = __builtin_amdgcn_mfma_f32_16x16x32_f16(av, cw, a2, 0, 0, 0);
        cw = nw;
      }
    }
  }
  __syncthreads();                               // b4: all P2 reads done

  // ---------- ph4: zero P3 border + write s2 output (oc = 2*row + ntb) ----------
  for (int j = tid; j < 576; j += 512) {         // 144 pos x 4 half8
    int u = j & 3, pos = j >> 2;
    int a = pos/12, c = pos - a*12;
    bool interior = ((unsigned)(a-2) < 8u) & ((unsigned)(c-2) < 8u);
    if (!interior) *(half8*)(P3 + pos*40 + u*8) = (half8)(_Float16)0.f;
  }
  {
    const int oc = 2*row + ntb;
    const float sA = bnc[64 + oc], hA = bnc[96 + oc];
    #pragma unroll
    for (int r = 0; r < 4; ++r) {
      int p2 = mtb*16 + kg*4 + r;
      int py2 = p2 >> 3, px2 = p2 & 7;
      int idx = ((py2+2)*12 + px2+2)*40;
      P3[idx + oc] = (_Float16)clamp01(fmaf(a2[r], sA, hA));
    }
  }
  __syncthreads();                               // b5: P3 complete

  // ---------- ph5: s3 MFMA (waves 0-3, wave = 16-oc N-tile); epilogue -> Ip3 ------
  if (w < 4) {
    const int py = row >> 2, px = row & 3;
    const _Float16* base = P3 + ((2*py)*12 + 2*px)*40 + kg*8;
    half8 RA[6], RB[6];
    #pragma unroll
    for (int c = 0; c < 6; ++c) RA[c] = *(const half8*)(base + c*40);
    #pragma unroll
    for (int c = 0; c < 6; ++c) RB[c] = *(const half8*)(base + 480 + c*40);
    const _Float16* wb = w3h + (w*16 + row)*32 + kg*8;
    half8 cw = *(const half8*)(wb);
    f32x4 a3 = {0,0,0,0};
    #pragma unroll
    for (int dy = 0; dy < 5; ++dy) {
      half8 cs[6];
      #pragma unroll
      for (int c = 0; c < 6; ++c) cs[c] = RA[c] + RB[c];
      if (dy < 4) {
        #pragma unroll
        for (int c = 0; c < 6; ++c) {
          half8 nv = *(const half8*)(base + (dy+2)*480 + c*40);
          if ((dy & 1) == 0) RA[c] = nv; else RB[c] = nv;
        }
      }
      #pragma unroll
      for (int dx = 0; dx < 5; ++dx) {
        const int tap = dy*5 + dx;
        const int tn = (tap < 24) ? tap + 1 : 24;
        half8 nw = *(const half8*)(wb + tn*2048);
        half8 av = cs[dx] + cs[dx+1];
        a3 = __builtin_amdgcn_mfma_f32_16x16x32_f16(av, cw, a3, 0, 0, 0);
        cw = nw;
      }
    }
    const int oc = w*16 + row;
    const float s3 = bnc[128 + oc], h3 = bnc[192 + oc];
    #pragma unroll
    for (int r = 0; r < 4; ++r)
      Ip3[(kg*4 + r)*64 + oc] = (_Float16)clamp01(fmaf(a3[r], s3, h3));
  }
  __syncthreads();                               // b6: Ip3 complete

  // ---------- ph6: fc 64x4x4 -> 10  + bn1d (VALU, f32 accum) ----------
  if (tid < 160) {
    const int oc = tid >> 4, pix = tid & 15;
    const _Float16* A = Ip3 + pix*64;
    const _Float16* W = w4h + oc*1024 + pix*64;
    float a = 0.f;
    #pragma unroll
    for (int q = 0; q < 8; ++q) {
      half8 xa = *(const half8*)(A + q*8);
      half8 wv = *(const half8*)(W + q*8);
      #pragma unroll
      for (int j = 0; j < 8; ++j)
        a = fmaf((float)xa[j], (float)wv[j], a);
    }
    S4P[tid] = a;
  }
  __syncthreads();                               // b7
  if (tid < 10) {
    float s = 0.f;
    #pragma unroll
    for (int i = 0; i < 16; ++i) s += S4P[tid*16 + i];
    out[img*10 + tid] = fmaf(s, bnc[256 + tid], bnc[266 + tid]);
  }
}

extern "C" void kernel_launch(void* const* d_in, const int* in_sizes, int n_in,
                              void* d_out, int out_size, void* d_ws, size_t ws_size,
                              hipStream_t stream)
{
  const float* x  = (const float*)d_in[0];
  const float* w1 = (const float*)d_in[1];
  const float* w2 = (const float*)d_in[2];
  const float* w3 = (const float*)d_in[3];
  const float* w4 = (const float*)d_in[4];
  const float *g1=(const float*)d_in[5],  *b1=(const float*)d_in[6],
              *m1=(const float*)d_in[7],  *v1=(const float*)d_in[8];
  const float *g2=(const float*)d_in[9],  *b2=(const float*)d_in[10],
              *m2=(const float*)d_in[11], *v2=(const float*)d_in[12];
  const float *g3=(const float*)d_in[13], *b3=(const float*)d_in[14],
              *m3=(const float*)d_in[15], *v3=(const float*)d_in[16];
  const float *g4=(const float*)d_in[17], *b4=(const float*)d_in[18],
              *m4=(const float*)d_in[19], *v4=(const float*)d_in[20];
  float* out = (float*)d_out;

  char* ws = (char*)d_ws;
  _Float16* w1h = (_Float16*)(ws);             //  10,240 B
  _Float16* w2h = (_Float16*)(ws + 10240);     //  51,200 B
  _Float16* w3h = (_Float16*)(ws + 61440);     // 102,400 B
  _Float16* w4h = (_Float16*)(ws + 163840);    //  32,768 B
  float*    bnc = (float*)   (ws + 196608);    //   1,152 B

  k_prep<<<dim3(128), dim3(256), 0, stream>>>(w1, w2, w3, w4,
      g1,b1,m1,v1, g2,b2,m2,v2, g3,b3,m3,v3, g4,b4,m4,v4,
      w1h, w2h, w3h, w4h, bnc);
  k_fused<<<dim3(1024), dim3(512), 0, stream>>>(x, w1h, w2h, w3h, w4h, bnc, out);
}